// Round 4
// baseline (282.534 us; speedup 1.0000x reference)
//
#include <hip/hip_runtime.h>

// Capsule routing B=32 I=64 J=1152 K=32 M=16, routings=3, via MFMA.
// u_hat[k,b] per (i,j) = one v_mfma_f32_32x32x16_bf16; split-bf16 hi/lo
// 3-MFMA keeps ~f32 accuracy; c applied post-MFMA in f32.
// i-tiled blocks (16 j x 8 i): x fragments split ONCE per block and reused
// across i (kills the 604MB/sweep x re-read traffic); W double-buffered
// across the i-loop. No atomics: k_s writes per-(jb,i) partials, k_redsq
// reduces + squashes. Softmax stored as (max, 1/sum) per (j,b).
// ws (floats): spart 4718592 | br 2359296 | m 36864 | z 36864 | ot 65536

#define Ii 64
#define Jj 1152
#define Kk 32
#define Bb 32
#define NJB2 72     // J / 16

typedef short  bf16x8 __attribute__((ext_vector_type(8)));
typedef float  f32x16 __attribute__((ext_vector_type(16)));
typedef float  f32x4  __attribute__((ext_vector_type(4)));

__device__ __forceinline__ void split2(float a, float b, unsigned &hi, unsigned &lo){
  unsigned ua = __float_as_uint(a), ub = __float_as_uint(b);
  unsigned ha = ua & 0xFFFF0000u, hb = ub & 0xFFFF0000u;
  hi = (ha >> 16) | hb;
  float la = a - __uint_as_float(ha);
  float lb = b - __uint_as_float(hb);
  lo = ((__float_as_uint(la) & 0xFFFF0000u) >> 16) | (__float_as_uint(lb) & 0xFFFF0000u);
}

__device__ __forceinline__ void split8(const float* v, bf16x8 &hi, bf16x8 &lo){
  union U { bf16x8 v; unsigned u[4]; } H, L;
#pragma unroll
  for (int p=0;p<4;p++) split2(v[2*p], v[2*p+1], H.u[p], L.u[p]);
  hi = H.v; lo = L.v;
}

#define MFMA(A,B,C) __builtin_amdgcn_mfma_f32_32x32x16_bf16(A,B,C,0,0,0)

// ---- s pass: block = (16 j) x (8 i); per-i partial to spart --------------
template<int FIRST>
__global__ __launch_bounds__(256, 2)
void k_s(const float* __restrict__ Wp, const float* __restrict__ xp,
         const float* __restrict__ brt, const float* __restrict__ mp,
         const float* __restrict__ zp, float* __restrict__ spart)
{
  __shared__ float red[4*1088];
  const int t  = threadIdx.x;
  const int w  = t >> 6, lane = t & 63;
  const int kk = lane & 31;
  const int h  = lane >> 5;
  const int b  = lane & 31;
  const int i0 = blockIdx.y * 8;
  const int j0 = blockIdx.x * 16 + w * 4;   // this wave's 4 j's

  // x fragments: load + split once, reuse across all 8 i
  bf16x8 Bh[4], Bl[4];
  float mzm[4], mzz[4];
#pragma unroll
  for (int jj=0;jj<4;jj++){
    const int j = j0 + jj;
    float x8[8];
    *(f32x4*)(x8)   = *(const f32x4*)(xp + (b*Jj + j)*16 + h*8);
    *(f32x4*)(x8+4) = *(const f32x4*)(xp + (b*Jj + j)*16 + h*8 + 4);
    split8(x8, Bh[jj], Bl[jj]);
    if (!FIRST){ mzm[jj] = mp[j*32+b]; mzz[jj] = zp[j*32+b]; }
  }

  float wb[2][4][8];
  float cb[2][4];
#pragma unroll
  for (int jj=0;jj<4;jj++){
    const float* wv = Wp + ((size_t)(i0*Jj + j0+jj)*512 + kk*16 + h*8);
    *(f32x4*)(wb[0][jj])   = *(const f32x4*)(wv);
    *(f32x4*)(wb[0][jj]+4) = *(const f32x4*)(wv+4);
    if (!FIRST) cb[0][jj] = brt[(i0*Jj + j0+jj)*32 + b];
  }

  for (int ii=0; ii<8; ++ii){
    const int i = i0 + ii;
    const int cur = ii & 1, nxt = cur ^ 1;
    if (ii < 7){
#pragma unroll
      for (int jj=0;jj<4;jj++){
        const float* wv = Wp + ((size_t)((i+1)*Jj + j0+jj)*512 + kk*16 + h*8);
        *(f32x4*)(wb[nxt][jj])   = *(const f32x4*)(wv);
        *(f32x4*)(wb[nxt][jj]+4) = *(const f32x4*)(wv+4);
        if (!FIRST) cb[nxt][jj] = brt[((i+1)*Jj + j0+jj)*32 + b];
      }
    }

    f32x16 acc = {};
#pragma unroll
    for (int jj=0;jj<4;jj++){
      bf16x8 Ah, Al;
      split8(wb[cur][jj], Ah, Al);
      f32x16 d = {};
      d = MFMA(Ah, Bh[jj], d);
      d = MFMA(Ah, Bl[jj], d);
      d = MFMA(Al, Bh[jj], d);
      const float cw = FIRST ? 0.015625f
                             : __expf(cb[cur][jj] - mzm[jj]) * mzz[jj];
#pragma unroll
      for (int r=0;r<16;r++) acc[r] += cw * d[r];
    }

    // cross-wave reduce for this i (stride-17 rows: conflict-free)
    __syncthreads();
#pragma unroll
    for (int r=0;r<16;r++) red[w*1088 + lane*17 + r] = acc[r];
    __syncthreads();
    f32x4 outv;
#pragma unroll
    for (int q=0;q<4;q++){
      const int v  = t*4 + q;
      const int lv = v >> 4, r = v & 15;
      float sum = 0.f;
#pragma unroll
      for (int ww=0;ww<4;ww++) sum += red[ww*1088 + lv*17 + r];
      outv[q] = sum;
    }
    *(f32x4*)&spart[((size_t)blockIdx.x*Ii + i)*1024 + t*4] = outv;
  }
}

// ---- reduce 72 partials + squash; TR=1 -> o_t[i][k][b], TR=0 -> out[b][i][k]
template<int TR>
__global__ __launch_bounds__(256)
void k_redsq(const float* __restrict__ spart, float* __restrict__ outp)
{
  const int i = blockIdx.x, t = threadIdx.x;
  f32x4 a = {0.f,0.f,0.f,0.f};
#pragma unroll 8
  for (int jb=0;jb<NJB2;jb++)
    a += *(const f32x4*)&spart[((size_t)jb*Ii + i)*1024 + t*4];

  const int b2 = (t>>2)&31, hh = t>>7, t3 = t&3;
  float ss = a.x*a.x + a.y*a.y + a.z*a.z + a.w*a.w;
  ss += __shfl_xor(ss,1);
  ss += __shfl_xor(ss,2);
  __shared__ float sp2[2][32];
  if (t3 == 0) sp2[hh][b2] = ss;
  __syncthreads();
  const float s2 = sp2[0][b2] + sp2[1][b2];
  const float scale = s2/(1.f+s2) * rsqrtf(s2 + 1e-7f);
#pragma unroll
  for (int q=0;q<4;q++){
    const int kcap = q + 8*t3 + 4*hh;
    const float val = a[q]*scale;
    if (TR) outp[(i*Kk + kcap)*Bb + b2] = val;
    else    outp[((size_t)b2*Ii + i)*Kk + kcap] = val;
  }
}

// ---- agree pass: block = (16 j) x (8 i); br_t[i][j][b] (+)= o.u_hat ------
template<int ADD>
__global__ __launch_bounds__(256, 2)
void k_ag(const float* __restrict__ Wp, const float* __restrict__ xp,
          const float* __restrict__ ot, float* __restrict__ brt)
{
  const int t  = threadIdx.x;
  const int w  = t >> 6, lane = t & 63;
  const int kk = lane & 31;
  const int h  = lane >> 5;
  const int b  = lane & 31;
  const int i0 = blockIdx.y * 8;
  const int j0 = blockIdx.x * 16 + w * 4;

  bf16x8 Bh[4], Bl[4];
#pragma unroll
  for (int jj=0;jj<4;jj++){
    const int j = j0 + jj;
    float x8[8];
    *(f32x4*)(x8)   = *(const f32x4*)(xp + (b*Jj + j)*16 + h*8);
    *(f32x4*)(x8+4) = *(const f32x4*)(xp + (b*Jj + j)*16 + h*8 + 4);
    split8(x8, Bh[jj], Bl[jj]);
  }

  float wb[2][4][8];
  float pv[2][4];
  float ov[2][16];
#pragma unroll
  for (int jj=0;jj<4;jj++){
    const float* wv = Wp + ((size_t)(i0*Jj + j0+jj)*512 + kk*16 + h*8);
    *(f32x4*)(wb[0][jj])   = *(const f32x4*)(wv);
    *(f32x4*)(wb[0][jj]+4) = *(const f32x4*)(wv+4);
    pv[0][jj] = ADD ? brt[(i0*Jj + j0+jj)*32 + b] : 0.f;
  }
#pragma unroll
  for (int r=0;r<16;r++){
    const int kcap = (r & 3) + 8*(r >> 2) + 4*h;
    ov[0][r] = ot[(i0*Kk + kcap)*Bb + b];
  }

  for (int ii=0; ii<8; ++ii){
    const int i = i0 + ii;
    const int cur = ii & 1, nxt = cur ^ 1;
    if (ii < 7){
#pragma unroll
      for (int jj=0;jj<4;jj++){
        const float* wv = Wp + ((size_t)((i+1)*Jj + j0+jj)*512 + kk*16 + h*8);
        *(f32x4*)(wb[nxt][jj])   = *(const f32x4*)(wv);
        *(f32x4*)(wb[nxt][jj]+4) = *(const f32x4*)(wv+4);
        pv[nxt][jj] = ADD ? brt[((i+1)*Jj + j0+jj)*32 + b] : 0.f;
      }
#pragma unroll
      for (int r=0;r<16;r++){
        const int kcap = (r & 3) + 8*(r >> 2) + 4*h;
        ov[nxt][r] = ot[((i+1)*Kk + kcap)*Bb + b];
      }
    }

#pragma unroll
    for (int jj=0;jj<4;jj++){
      bf16x8 Ah, Al;
      split8(wb[cur][jj], Ah, Al);
      f32x16 d = {};
      d = MFMA(Ah, Bh[jj], d);
      d = MFMA(Ah, Bl[jj], d);
      d = MFMA(Al, Bh[jj], d);
      float ap = 0.f;
#pragma unroll
      for (int r=0;r<16;r++) ap += ov[cur][r]*d[r];
      ap += __shfl_xor(ap, 32);
      if (h == 0)
        brt[(i*Jj + j0+jj)*32 + b] = pv[cur][jj] + ap;
    }
  }
}

// ---- per-(j,b) softmax stats over i: m = max_i b, z = 1/sum exp(b-m) -----
__global__ __launch_bounds__(256)
void k_norm(const float* __restrict__ brt, float* __restrict__ mp,
            float* __restrict__ zp)
{
  const int t  = threadIdx.x;
  const int jl = t >> 5, b = t & 31;
  const int j  = blockIdx.x*8 + jl;
  float v[64];
  float mx = -1e30f;
#pragma unroll
  for (int ii=0; ii<64; ++ii){
    v[ii] = brt[(ii*Jj + j)*32 + b];
    mx = fmaxf(mx, v[ii]);
  }
  float sum = 0.f;
#pragma unroll
  for (int ii=0; ii<64; ++ii) sum += __expf(v[ii]-mx);
  mp[j*32 + b] = mx;
  zp[j*32 + b] = 1.f/sum;
}

extern "C" void kernel_launch(void* const* d_in, const int* in_sizes, int n_in,
                              void* d_out, int out_size, void* d_ws, size_t ws_size,
                              hipStream_t stream)
{
  const float* x  = (const float*)d_in[0];   // [B,J,M]
  const float* Wp = (const float*)d_in[1];   // [I,J,K,M]
  float* out = (float*)d_out;                // [B,I,K]
  float* ws  = (float*)d_ws;
  float* spart = ws;                         // 4718592 floats
  float* br    = ws + 4718592;               // 2359296
  float* m     = ws + 7077888;               // 36864
  float* z     = ws + 7114752;               // 36864
  float* ot    = ws + 7151616;               // 65536

  dim3 gs(NJB2, 8), bs(256);

  // iter 0 (c uniform 1/64)
  k_s<1><<<gs, bs, 0, stream>>>(Wp, x, nullptr, nullptr, nullptr, spart);
  k_redsq<1><<<dim3(64), bs, 0, stream>>>(spart, ot);
  k_ag<0><<<gs, bs, 0, stream>>>(Wp, x, ot, br);
  k_norm<<<dim3(144), bs, 0, stream>>>(br, m, z);

  // iter 1
  k_s<0><<<gs, bs, 0, stream>>>(Wp, x, br, m, z, spart);
  k_redsq<1><<<dim3(64), bs, 0, stream>>>(spart, ot);
  k_ag<1><<<gs, bs, 0, stream>>>(Wp, x, ot, br);
  k_norm<<<dim3(144), bs, 0, stream>>>(br, m, z);

  // iter 2
  k_s<0><<<gs, bs, 0, stream>>>(Wp, x, br, m, z, spart);
  k_redsq<0><<<dim3(64), bs, 0, stream>>>(spart, out);
}

// Round 5
// 185.630 us; speedup vs baseline: 1.5220x; 1.5220x over previous
//
#include <hip/hip_runtime.h>

// Capsule routing B=32 I=64 J=1152 K=32 M=16, routings=3, via MFMA.
// u_hat[k,b] per (i,j) = one v_mfma_f32_32x32x16_bf16; split-bf16 hi/lo
// 3-MFMA keeps ~f32 accuracy; c applied post-MFMA in f32.
// i-tile = 4 with FULLY UNROLLED i-loop (all array indices compile-time:
// round-4's runtime cur/nxt indexing put buffers in scratch -> 175MB
// scratch traffic). x fragments split once per block, reused across 4 i.
// No atomics: k_s writes per-(jb,i) partials, k_redsq reduces + squashes.
// Softmax stored as (max, 1/sum) per (j,b).
// ws (floats): spart 4718592 | br 2359296 | m 36864 | z 36864 | ot 65536

#define Ii 64
#define Jj 1152
#define Kk 32
#define Bb 32
#define NJB2 72     // J / 16

typedef short  bf16x8 __attribute__((ext_vector_type(8)));
typedef float  f32x16 __attribute__((ext_vector_type(16)));
typedef float  f32x4  __attribute__((ext_vector_type(4)));

__device__ __forceinline__ void split2(float a, float b, unsigned &hi, unsigned &lo){
  unsigned ua = __float_as_uint(a), ub = __float_as_uint(b);
  unsigned ha = ua & 0xFFFF0000u, hb = ub & 0xFFFF0000u;
  hi = (ha >> 16) | hb;
  float la = a - __uint_as_float(ha);
  float lb = b - __uint_as_float(hb);
  lo = ((__float_as_uint(la) & 0xFFFF0000u) >> 16) | (__float_as_uint(lb) & 0xFFFF0000u);
}

__device__ __forceinline__ void split8(const float* v, bf16x8 &hi, bf16x8 &lo){
  union U { bf16x8 v; unsigned u[4]; } H, L;
#pragma unroll
  for (int p=0;p<4;p++) split2(v[2*p], v[2*p+1], H.u[p], L.u[p]);
  hi = H.v; lo = L.v;
}

#define MFMA(A,B,C) __builtin_amdgcn_mfma_f32_32x32x16_bf16(A,B,C,0,0,0)

// ---- s pass: block = (16 j) x (4 i); acc in regs, reduce in epilogue -----
template<int FIRST>
__global__ __launch_bounds__(256, 2)
void k_s(const float* __restrict__ Wp, const float* __restrict__ xp,
         const float* __restrict__ brt, const float* __restrict__ mp,
         const float* __restrict__ zp, float* __restrict__ spart)
{
  __shared__ float red[4*1088];
  const int t  = threadIdx.x;
  const int w  = t >> 6, lane = t & 63;
  const int kk = lane & 31;
  const int h  = lane >> 5;
  const int b  = lane & 31;
  const int i0 = blockIdx.y * 4;
  const int j0 = blockIdx.x * 16 + w * 4;   // this wave's 4 j's

  // x fragments: load + split once, reuse across all 4 i
  bf16x8 Bh[4], Bl[4];
  float mzm[4], mzz[4];
#pragma unroll
  for (int jj=0;jj<4;jj++){
    const int j = j0 + jj;
    float x8[8];
    *(f32x4*)(x8)   = *(const f32x4*)(xp + (b*Jj + j)*16 + h*8);
    *(f32x4*)(x8+4) = *(const f32x4*)(xp + (b*Jj + j)*16 + h*8 + 4);
    split8(x8, Bh[jj], Bl[jj]);
    if (!FIRST){ mzm[jj] = mp[j*32+b]; mzz[jj] = zp[j*32+b]; }
  }

  f32x16 acc[4];
#pragma unroll
  for (int ii=0;ii<4;ii++) acc[ii] = {};

#pragma unroll
  for (int ii=0; ii<4; ++ii){
    const int i = i0 + ii;
#pragma unroll
    for (int jj=0;jj<4;jj++){
      float w8[8];
      const float* wv = Wp + ((size_t)(i*Jj + j0+jj)*512 + kk*16 + h*8);
      *(f32x4*)(w8)   = *(const f32x4*)(wv);
      *(f32x4*)(w8+4) = *(const f32x4*)(wv+4);
      bf16x8 Ah, Al;
      split8(w8, Ah, Al);
      f32x16 d = {};
      d = MFMA(Ah, Bh[jj], d);
      d = MFMA(Ah, Bl[jj], d);
      d = MFMA(Al, Bh[jj], d);
      float cw;
      if (FIRST) cw = 0.015625f;
      else {
        const float bv = brt[(i*Jj + j0+jj)*32 + b];
        cw = __expf(bv - mzm[jj]) * mzz[jj];
      }
#pragma unroll
      for (int r=0;r<16;r++) acc[ii][r] += cw * d[r];
    }
  }

  // epilogue: cross-wave reduce per i (stride-17 rows: conflict-free)
#pragma unroll
  for (int ii=0; ii<4; ++ii){
    __syncthreads();
#pragma unroll
    for (int r=0;r<16;r++) red[w*1088 + lane*17 + r] = acc[ii][r];
    __syncthreads();
    f32x4 outv;
#pragma unroll
    for (int q=0;q<4;q++){
      const int v  = t*4 + q;
      const int lv = v >> 4, r = v & 15;
      float sum = 0.f;
#pragma unroll
      for (int ww=0;ww<4;ww++) sum += red[ww*1088 + lv*17 + r];
      outv[q] = sum;
    }
    *(f32x4*)&spart[((size_t)blockIdx.x*Ii + (i0+ii))*1024 + t*4] = outv;
  }
}

// ---- reduce 72 partials + squash; TR=1 -> o_t[i][k][b], TR=0 -> out[b][i][k]
template<int TR>
__global__ __launch_bounds__(256)
void k_redsq(const float* __restrict__ spart, float* __restrict__ outp)
{
  const int i = blockIdx.x, t = threadIdx.x;
  f32x4 a = {0.f,0.f,0.f,0.f};
#pragma unroll 8
  for (int jb=0;jb<NJB2;jb++)
    a += *(const f32x4*)&spart[((size_t)jb*Ii + i)*1024 + t*4];

  const int b2 = (t>>2)&31, hh = t>>7, t3 = t&3;
  float ss = a.x*a.x + a.y*a.y + a.z*a.z + a.w*a.w;
  ss += __shfl_xor(ss,1);
  ss += __shfl_xor(ss,2);
  __shared__ float sp2[2][32];
  if (t3 == 0) sp2[hh][b2] = ss;
  __syncthreads();
  const float s2 = sp2[0][b2] + sp2[1][b2];
  const float scale = s2/(1.f+s2) * rsqrtf(s2 + 1e-7f);
#pragma unroll
  for (int q=0;q<4;q++){
    const int kcap = q + 8*t3 + 4*hh;
    const float val = a[q]*scale;
    if (TR) outp[(i*Kk + kcap)*Bb + b2] = val;
    else    outp[((size_t)b2*Ii + i)*Kk + kcap] = val;
  }
}

// ---- agree pass: block = (16 j) x (4 i); br_t[i][j][b] (+)= o.u_hat ------
template<int ADD>
__global__ __launch_bounds__(256, 2)
void k_ag(const float* __restrict__ Wp, const float* __restrict__ xp,
          const float* __restrict__ ot, float* __restrict__ brt)
{
  const int t  = threadIdx.x;
  const int w  = t >> 6, lane = t & 63;
  const int kk = lane & 31;
  const int h  = lane >> 5;
  const int b  = lane & 31;
  const int i0 = blockIdx.y * 4;
  const int j0 = blockIdx.x * 16 + w * 4;

  bf16x8 Bh[4], Bl[4];
#pragma unroll
  for (int jj=0;jj<4;jj++){
    const int j = j0 + jj;
    float x8[8];
    *(f32x4*)(x8)   = *(const f32x4*)(xp + (b*Jj + j)*16 + h*8);
    *(f32x4*)(x8+4) = *(const f32x4*)(xp + (b*Jj + j)*16 + h*8 + 4);
    split8(x8, Bh[jj], Bl[jj]);
  }

#pragma unroll
  for (int ii=0; ii<4; ++ii){
    const int i = i0 + ii;
    float ov[16];
#pragma unroll
    for (int r=0;r<16;r++){
      const int kcap = (r & 3) + 8*(r >> 2) + 4*h;
      ov[r] = ot[(i*Kk + kcap)*Bb + b];
    }
#pragma unroll
    for (int jj=0;jj<4;jj++){
      float w8[8];
      const float* wv = Wp + ((size_t)(i*Jj + j0+jj)*512 + kk*16 + h*8);
      *(f32x4*)(w8)   = *(const f32x4*)(wv);
      *(f32x4*)(w8+4) = *(const f32x4*)(wv+4);
      bf16x8 Ah, Al;
      split8(w8, Ah, Al);
      f32x16 d = {};
      d = MFMA(Ah, Bh[jj], d);
      d = MFMA(Ah, Bl[jj], d);
      d = MFMA(Al, Bh[jj], d);
      float ap = 0.f;
#pragma unroll
      for (int r=0;r<16;r++) ap += ov[r]*d[r];
      ap += __shfl_xor(ap, 32);
      if (h == 0){
        const int idx = (i*Jj + j0+jj)*32 + b;
        const float prev = ADD ? brt[idx] : 0.f;
        brt[idx] = prev + ap;
      }
    }
  }
}

// ---- per-(j,b) softmax stats over i: m = max_i b, z = 1/sum exp(b-m) -----
__global__ __launch_bounds__(256)
void k_norm(const float* __restrict__ brt, float* __restrict__ mp,
            float* __restrict__ zp)
{
  const int t  = threadIdx.x;
  const int jl = t >> 5, b = t & 31;
  const int j  = blockIdx.x*8 + jl;
  float v[64];
  float mx = -1e30f;
#pragma unroll
  for (int ii=0; ii<64; ++ii){
    v[ii] = brt[(ii*Jj + j)*32 + b];
    mx = fmaxf(mx, v[ii]);
  }
  float sum = 0.f;
#pragma unroll
  for (int ii=0; ii<64; ++ii) sum += __expf(v[ii]-mx);
  mp[j*32 + b] = mx;
  zp[j*32 + b] = 1.f/sum;
}

extern "C" void kernel_launch(void* const* d_in, const int* in_sizes, int n_in,
                              void* d_out, int out_size, void* d_ws, size_t ws_size,
                              hipStream_t stream)
{
  const float* x  = (const float*)d_in[0];   // [B,J,M]
  const float* Wp = (const float*)d_in[1];   // [I,J,K,M]
  float* out = (float*)d_out;                // [B,I,K]
  float* ws  = (float*)d_ws;
  float* spart = ws;                         // 4718592 floats
  float* br    = ws + 4718592;               // 2359296
  float* m     = ws + 7077888;               // 36864
  float* z     = ws + 7114752;               // 36864
  float* ot    = ws + 7151616;               // 65536

  dim3 gs(NJB2, 16), bs(256);

  // iter 0 (c uniform 1/64)
  k_s<1><<<gs, bs, 0, stream>>>(Wp, x, nullptr, nullptr, nullptr, spart);
  k_redsq<1><<<dim3(64), bs, 0, stream>>>(spart, ot);
  k_ag<0><<<gs, bs, 0, stream>>>(Wp, x, ot, br);
  k_norm<<<dim3(144), bs, 0, stream>>>(br, m, z);

  // iter 1
  k_s<0><<<gs, bs, 0, stream>>>(Wp, x, br, m, z, spart);
  k_redsq<1><<<dim3(64), bs, 0, stream>>>(spart, ot);
  k_ag<1><<<gs, bs, 0, stream>>>(Wp, x, ot, br);
  k_norm<<<dim3(144), bs, 0, stream>>>(br, m, z);

  // iter 2
  k_s<0><<<gs, bs, 0, stream>>>(Wp, x, br, m, z, spart);
  k_redsq<0><<<dim3(64), bs, 0, stream>>>(spart, out);
}

// Round 6
// 142.300 us; speedup vs baseline: 1.9855x; 1.3045x over previous
//
#include <hip/hip_runtime.h>

// Capsule routing B=32 I=64 J=1152 K=32 M=16, routings=3, via MFMA.
// u_hat[k,b] per (i,j) = one v_mfma_f32_32x32x16_bf16.
// Sweep 1 (k_s<1>) streams f32 W with full split-bf16 3-MFMA accuracy AND
// writes the hi-bf16 W copy (75.5MB). Sweeps 2-5 read bf16 W (half traffic,
// L3-retainable) with 2 MFMA (W-hi * x-hi + W-hi * x-lo); x stays split for
// accuracy. All loop indices compile-time (rule #20). No atomics: k_s writes
// per-(jb,i) partials, k_redsq reduces + squashes. Softmax stored as
// (max, 1/sum) per (j,b).
// ws (floats): spart 4718592 | br 2359296 | m 36864 | z 36864 | ot 65536 |
//              Wbf 9437184 (ushort*2)

#define Ii 64
#define Jj 1152
#define Kk 32
#define Bb 32
#define NJB2 72     // J / 16

typedef short  bf16x8 __attribute__((ext_vector_type(8)));
typedef float  f32x16 __attribute__((ext_vector_type(16)));
typedef float  f32x4  __attribute__((ext_vector_type(4)));

__device__ __forceinline__ void split2(float a, float b, unsigned &hi, unsigned &lo){
  unsigned ua = __float_as_uint(a), ub = __float_as_uint(b);
  unsigned ha = ua & 0xFFFF0000u, hb = ub & 0xFFFF0000u;
  hi = (ha >> 16) | hb;
  float la = a - __uint_as_float(ha);
  float lb = b - __uint_as_float(hb);
  lo = ((__float_as_uint(la) & 0xFFFF0000u) >> 16) | (__float_as_uint(lb) & 0xFFFF0000u);
}

__device__ __forceinline__ void split8(const float* v, bf16x8 &hi, bf16x8 &lo){
  union U { bf16x8 v; unsigned u[4]; } H, L;
#pragma unroll
  for (int p=0;p<4;p++) split2(v[2*p], v[2*p+1], H.u[p], L.u[p]);
  hi = H.v; lo = L.v;
}

#define MFMA(A,B,C) __builtin_amdgcn_mfma_f32_32x32x16_bf16(A,B,C,0,0,0)

// ---- s pass: block = (16 j) x (4 i); acc in regs, reduce in epilogue -----
// FIRST=1: read f32 W, emit bf16 W, 3-MFMA split. FIRST=0: read bf16 W, 2-MFMA.
template<int FIRST>
__global__ __launch_bounds__(256, 2)
void k_s(const float* __restrict__ Wp, const ushort* __restrict__ Wbi,
         ushort* __restrict__ Wbo, const float* __restrict__ xp,
         const float* __restrict__ brt, const float* __restrict__ mp,
         const float* __restrict__ zp, float* __restrict__ spart)
{
  __shared__ float red[4*1088];
  const int t  = threadIdx.x;
  const int w  = t >> 6, lane = t & 63;
  const int kk = lane & 31;
  const int h  = lane >> 5;
  const int b  = lane & 31;
  const int i0 = blockIdx.y * 4;
  const int j0 = blockIdx.x * 16 + w * 4;   // this wave's 4 j's

  // x fragments: load + split once, reuse across all 4 i
  bf16x8 Bh[4], Bl[4];
  float mzm[4], mzz[4];
#pragma unroll
  for (int jj=0;jj<4;jj++){
    const int j = j0 + jj;
    float x8[8];
    *(f32x4*)(x8)   = *(const f32x4*)(xp + (b*Jj + j)*16 + h*8);
    *(f32x4*)(x8+4) = *(const f32x4*)(xp + (b*Jj + j)*16 + h*8 + 4);
    split8(x8, Bh[jj], Bl[jj]);
    if (!FIRST){ mzm[jj] = mp[j*32+b]; mzz[jj] = zp[j*32+b]; }
  }

  f32x16 acc[4];
#pragma unroll
  for (int ii=0;ii<4;ii++) acc[ii] = {};

#pragma unroll
  for (int ii=0; ii<4; ++ii){
    const int i = i0 + ii;
#pragma unroll
    for (int jj=0;jj<4;jj++){
      const size_t eoff = (size_t)(i*Jj + j0+jj)*512 + kk*16 + h*8;
      f32x16 d = {};
      if (FIRST){
        float w8[8];
        *(f32x4*)(w8)   = *(const f32x4*)(Wp + eoff);
        *(f32x4*)(w8+4) = *(const f32x4*)(Wp + eoff + 4);
        bf16x8 Ah, Al;
        split8(w8, Ah, Al);
        *reinterpret_cast<bf16x8*>(Wbo + eoff) = Ah;   // emit bf16 W
        d = MFMA(Ah, Bh[jj], d);
        d = MFMA(Ah, Bl[jj], d);
        d = MFMA(Al, Bh[jj], d);
      } else {
        const bf16x8 Ah = *reinterpret_cast<const bf16x8*>(Wbi + eoff);
        d = MFMA(Ah, Bh[jj], d);
        d = MFMA(Ah, Bl[jj], d);
      }
      float cw;
      if (FIRST) cw = 0.015625f;
      else {
        const float bv = brt[(i*Jj + j0+jj)*32 + b];
        cw = __expf(bv - mzm[jj]) * mzz[jj];
      }
#pragma unroll
      for (int r=0;r<16;r++) acc[ii][r] += cw * d[r];
    }
  }

  // epilogue: cross-wave reduce per i (stride-17 rows: conflict-free)
#pragma unroll
  for (int ii=0; ii<4; ++ii){
    __syncthreads();
#pragma unroll
    for (int r=0;r<16;r++) red[w*1088 + lane*17 + r] = acc[ii][r];
    __syncthreads();
    f32x4 outv;
#pragma unroll
    for (int q=0;q<4;q++){
      const int v  = t*4 + q;
      const int lv = v >> 4, r = v & 15;
      float sum = 0.f;
#pragma unroll
      for (int ww=0;ww<4;ww++) sum += red[ww*1088 + lv*17 + r];
      outv[q] = sum;
    }
    *(f32x4*)&spart[((size_t)blockIdx.x*Ii + (i0+ii))*1024 + t*4] = outv;
  }
}

// ---- reduce 72 partials + squash; TR=1 -> o_t[i][k][b], TR=0 -> out[b][i][k]
template<int TR>
__global__ __launch_bounds__(256)
void k_redsq(const float* __restrict__ spart, float* __restrict__ outp)
{
  const int i = blockIdx.x, t = threadIdx.x;
  f32x4 a = {0.f,0.f,0.f,0.f};
#pragma unroll 8
  for (int jb=0;jb<NJB2;jb++)
    a += *(const f32x4*)&spart[((size_t)jb*Ii + i)*1024 + t*4];

  const int b2 = (t>>2)&31, hh = t>>7, t3 = t&3;
  float ss = a.x*a.x + a.y*a.y + a.z*a.z + a.w*a.w;
  ss += __shfl_xor(ss,1);
  ss += __shfl_xor(ss,2);
  __shared__ float sp2[2][32];
  if (t3 == 0) sp2[hh][b2] = ss;
  __syncthreads();
  const float s2 = sp2[0][b2] + sp2[1][b2];
  const float scale = s2/(1.f+s2) * rsqrtf(s2 + 1e-7f);
#pragma unroll
  for (int q=0;q<4;q++){
    const int kcap = q + 8*t3 + 4*hh;
    const float val = a[q]*scale;
    if (TR) outp[(i*Kk + kcap)*Bb + b2] = val;
    else    outp[((size_t)b2*Ii + i)*Kk + kcap] = val;
  }
}

// ---- agree pass (bf16 W): block = (16 j) x (4 i); br_t (+)= o.u_hat ------
template<int ADD>
__global__ __launch_bounds__(256, 2)
void k_ag(const ushort* __restrict__ Wb, const float* __restrict__ xp,
          const float* __restrict__ ot, float* __restrict__ brt)
{
  const int t  = threadIdx.x;
  const int w  = t >> 6, lane = t & 63;
  const int kk = lane & 31;
  const int h  = lane >> 5;
  const int b  = lane & 31;
  const int i0 = blockIdx.y * 4;
  const int j0 = blockIdx.x * 16 + w * 4;

  bf16x8 Bh[4], Bl[4];
#pragma unroll
  for (int jj=0;jj<4;jj++){
    const int j = j0 + jj;
    float x8[8];
    *(f32x4*)(x8)   = *(const f32x4*)(xp + (b*Jj + j)*16 + h*8);
    *(f32x4*)(x8+4) = *(const f32x4*)(xp + (b*Jj + j)*16 + h*8 + 4);
    split8(x8, Bh[jj], Bl[jj]);
  }

#pragma unroll
  for (int ii=0; ii<4; ++ii){
    const int i = i0 + ii;
    float ov[16];
#pragma unroll
    for (int r=0;r<16;r++){
      const int kcap = (r & 3) + 8*(r >> 2) + 4*h;
      ov[r] = ot[(i*Kk + kcap)*Bb + b];
    }
#pragma unroll
    for (int jj=0;jj<4;jj++){
      const size_t eoff = (size_t)(i*Jj + j0+jj)*512 + kk*16 + h*8;
      const bf16x8 Ah = *reinterpret_cast<const bf16x8*>(Wb + eoff);
      f32x16 d = {};
      d = MFMA(Ah, Bh[jj], d);
      d = MFMA(Ah, Bl[jj], d);
      float ap = 0.f;
#pragma unroll
      for (int r=0;r<16;r++) ap += ov[r]*d[r];
      ap += __shfl_xor(ap, 32);
      if (h == 0){
        const int idx = (i*Jj + j0+jj)*32 + b;
        const float prev = ADD ? brt[idx] : 0.f;
        brt[idx] = prev + ap;
      }
    }
  }
}

// ---- per-(j,b) softmax stats over i: m = max_i b, z = 1/sum exp(b-m) -----
__global__ __launch_bounds__(256)
void k_norm(const float* __restrict__ brt, float* __restrict__ mp,
            float* __restrict__ zp)
{
  const int t  = threadIdx.x;
  const int jl = t >> 5, b = t & 31;
  const int j  = blockIdx.x*8 + jl;
  float v[64];
  float mx = -1e30f;
#pragma unroll
  for (int ii=0; ii<64; ++ii){
    v[ii] = brt[(ii*Jj + j)*32 + b];
    mx = fmaxf(mx, v[ii]);
  }
  float sum = 0.f;
#pragma unroll
  for (int ii=0; ii<64; ++ii) sum += __expf(v[ii]-mx);
  mp[j*32 + b] = mx;
  zp[j*32 + b] = 1.f/sum;
}

extern "C" void kernel_launch(void* const* d_in, const int* in_sizes, int n_in,
                              void* d_out, int out_size, void* d_ws, size_t ws_size,
                              hipStream_t stream)
{
  const float* x  = (const float*)d_in[0];   // [B,J,M]
  const float* Wp = (const float*)d_in[1];   // [I,J,K,M]
  float* out = (float*)d_out;                // [B,I,K]
  float* ws  = (float*)d_ws;
  float* spart = ws;                         // 4718592 floats
  float* br    = ws + 4718592;               // 2359296
  float* m     = ws + 7077888;               // 36864
  float* z     = ws + 7114752;               // 36864
  float* ot    = ws + 7151616;               // 65536
  ushort* Wbf  = (ushort*)(ws + 7217152);    // 18874368 ushorts (36MB)

  dim3 gs(NJB2, 16), bs(256);

  // iter 0 (c uniform 1/64); k_s<1> also emits bf16 W
  k_s<1><<<gs, bs, 0, stream>>>(Wp, nullptr, Wbf, x, nullptr, nullptr, nullptr, spart);
  k_redsq<1><<<dim3(64), bs, 0, stream>>>(spart, ot);
  k_ag<0><<<gs, bs, 0, stream>>>(Wbf, x, ot, br);
  k_norm<<<dim3(144), bs, 0, stream>>>(br, m, z);

  // iter 1
  k_s<0><<<gs, bs, 0, stream>>>(nullptr, Wbf, nullptr, x, br, m, z, spart);
  k_redsq<1><<<dim3(64), bs, 0, stream>>>(spart, ot);
  k_ag<1><<<gs, bs, 0, stream>>>(Wbf, x, ot, br);
  k_norm<<<dim3(144), bs, 0, stream>>>(br, m, z);

  // iter 2
  k_s<0><<<gs, bs, 0, stream>>>(nullptr, Wbf, nullptr, x, br, m, z, spart);
  k_redsq<0><<<dim3(64), bs, 0, stream>>>(spart, out);
}

// Round 7
// 136.316 us; speedup vs baseline: 2.0726x; 1.0439x over previous
//
#include <hip/hip_runtime.h>

// Capsule routing B=32 I=64 J=1152 K=32 M=16, routings=3, via MFMA.
// u_hat[k,b] per (i,j) = one v_mfma_f32_32x32x16_bf16.
// Sweep 1 (k_s<1>) streams f32 W (3-MFMA split accuracy) AND emits bf16 W.
// Sweeps 2-5 read bf16 W (2 MFMA; x stays hi/lo split).
// Round-7: spart stored bf16 (halves its round-trip); softmax WITHOUT
// max-subtraction (|b|<~25, f32-safe) so denominator z is accumulated by
// atomicAdd inside k_ag -> k_norm eliminated; k_s uses c = exp(b)/z.
// All loop indices compile-time (rule #20). No s-atomics: k_s writes
// per-(jb,i) partials, k_redsq reduces + squashes.
// ws: spart ushort[72*64*1024] | br f32[2359296] | z f32[36864] |
//     ot f32[65536] | Wbf ushort[37748736]

#define Ii 64
#define Jj 1152
#define Kk 32
#define Bb 32
#define NJB2 72     // J / 16

typedef short  bf16x8 __attribute__((ext_vector_type(8)));
typedef float  f32x16 __attribute__((ext_vector_type(16)));
typedef float  f32x4  __attribute__((ext_vector_type(4)));

__device__ __forceinline__ void split2(float a, float b, unsigned &hi, unsigned &lo){
  unsigned ua = __float_as_uint(a), ub = __float_as_uint(b);
  unsigned ha = ua & 0xFFFF0000u, hb = ub & 0xFFFF0000u;
  hi = (ha >> 16) | hb;
  float la = a - __uint_as_float(ha);
  float lb = b - __uint_as_float(hb);
  lo = ((__float_as_uint(la) & 0xFFFF0000u) >> 16) | (__float_as_uint(lb) & 0xFFFF0000u);
}

__device__ __forceinline__ void split8(const float* v, bf16x8 &hi, bf16x8 &lo){
  union U { bf16x8 v; unsigned u[4]; } H, L;
#pragma unroll
  for (int p=0;p<4;p++) split2(v[2*p], v[2*p+1], H.u[p], L.u[p]);
  hi = H.v; lo = L.v;
}

__device__ __forceinline__ ushort f2bf_rne(float f){
  unsigned u = __float_as_uint(f);
  return (ushort)((u + 0x7FFFu + ((u >> 16) & 1u)) >> 16);
}

#define MFMA(A,B,C) __builtin_amdgcn_mfma_f32_32x32x16_bf16(A,B,C,0,0,0)

// ---- s pass: block = (16 j) x (4 i); acc in regs, reduce in epilogue -----
// FIRST=1: read f32 W, emit bf16 W, 3-MFMA split. FIRST=0: read bf16 W, 2-MFMA.
template<int FIRST>
__global__ __launch_bounds__(256, 2)
void k_s(const float* __restrict__ Wp, const ushort* __restrict__ Wbi,
         ushort* __restrict__ Wbo, const float* __restrict__ xp,
         const float* __restrict__ brt, const float* __restrict__ zp,
         ushort* __restrict__ spart)
{
  __shared__ float red[4*1088];
  const int t  = threadIdx.x;
  const int w  = t >> 6, lane = t & 63;
  const int kk = lane & 31;
  const int h  = lane >> 5;
  const int b  = lane & 31;
  const int i0 = blockIdx.y * 4;
  const int j0 = blockIdx.x * 16 + w * 4;   // this wave's 4 j's

  // x fragments: load + split once, reuse across all 4 i
  bf16x8 Bh[4], Bl[4];
  float zi[4];
#pragma unroll
  for (int jj=0;jj<4;jj++){
    const int j = j0 + jj;
    float x8[8];
    *(f32x4*)(x8)   = *(const f32x4*)(xp + (b*Jj + j)*16 + h*8);
    *(f32x4*)(x8+4) = *(const f32x4*)(xp + (b*Jj + j)*16 + h*8 + 4);
    split8(x8, Bh[jj], Bl[jj]);
    if (!FIRST) zi[jj] = 1.0f / zp[j*32 + b];
  }

  f32x16 acc[4];
#pragma unroll
  for (int ii=0;ii<4;ii++) acc[ii] = {};

#pragma unroll
  for (int ii=0; ii<4; ++ii){
    const int i = i0 + ii;
#pragma unroll
    for (int jj=0;jj<4;jj++){
      const size_t eoff = (size_t)(i*Jj + j0+jj)*512 + kk*16 + h*8;
      f32x16 d = {};
      if (FIRST){
        float w8[8];
        *(f32x4*)(w8)   = *(const f32x4*)(Wp + eoff);
        *(f32x4*)(w8+4) = *(const f32x4*)(Wp + eoff + 4);
        bf16x8 Ah, Al;
        split8(w8, Ah, Al);
        *reinterpret_cast<bf16x8*>(Wbo + eoff) = Ah;   // emit bf16 W
        d = MFMA(Ah, Bh[jj], d);
        d = MFMA(Ah, Bl[jj], d);
        d = MFMA(Al, Bh[jj], d);
      } else {
        const bf16x8 Ah = *reinterpret_cast<const bf16x8*>(Wbi + eoff);
        d = MFMA(Ah, Bh[jj], d);
        d = MFMA(Ah, Bl[jj], d);
      }
      float cw;
      if (FIRST) cw = 0.015625f;
      else {
        const float bv = brt[(i*Jj + j0+jj)*32 + b];
        cw = __expf(bv) * zi[jj];
      }
#pragma unroll
      for (int r=0;r<16;r++) acc[ii][r] += cw * d[r];
    }
  }

  // epilogue: cross-wave reduce per i (stride-17 rows: conflict-free)
#pragma unroll
  for (int ii=0; ii<4; ++ii){
    __syncthreads();
#pragma unroll
    for (int r=0;r<16;r++) red[w*1088 + lane*17 + r] = acc[ii][r];
    __syncthreads();
    ushort4 outv;
    {
      float sx, sy, sz, sw;
#pragma unroll
      for (int q=0;q<4;q++){
        const int v  = t*4 + q;
        const int lv = v >> 4, r = v & 15;
        float sum = 0.f;
#pragma unroll
        for (int ww=0;ww<4;ww++) sum += red[ww*1088 + lv*17 + r];
        if (q==0) sx=sum; else if (q==1) sy=sum; else if (q==2) sz=sum; else sw=sum;
      }
      outv.x = f2bf_rne(sx); outv.y = f2bf_rne(sy);
      outv.z = f2bf_rne(sz); outv.w = f2bf_rne(sw);
    }
    *(ushort4*)&spart[((size_t)blockIdx.x*Ii + (i0+ii))*1024 + t*4] = outv;
  }
}

// ---- reduce 72 bf16 partials + squash; TR=1 -> o_t[i][k][b], else out ----
template<int TR>
__global__ __launch_bounds__(256)
void k_redsq(const ushort* __restrict__ spart, float* __restrict__ outp)
{
  const int i = blockIdx.x, t = threadIdx.x;
  float a0=0.f, a1=0.f, a2=0.f, a3=0.f;
#pragma unroll 8
  for (int jb=0;jb<NJB2;jb++){
    const ushort4 u = *(const ushort4*)&spart[((size_t)jb*Ii + i)*1024 + t*4];
    a0 += __uint_as_float((unsigned)u.x << 16);
    a1 += __uint_as_float((unsigned)u.y << 16);
    a2 += __uint_as_float((unsigned)u.z << 16);
    a3 += __uint_as_float((unsigned)u.w << 16);
  }

  const int b2 = (t>>2)&31, hh = t>>7, t3 = t&3;
  float ss = a0*a0 + a1*a1 + a2*a2 + a3*a3;
  ss += __shfl_xor(ss,1);
  ss += __shfl_xor(ss,2);
  __shared__ float sp2[2][32];
  if (t3 == 0) sp2[hh][b2] = ss;
  __syncthreads();
  const float s2 = sp2[0][b2] + sp2[1][b2];
  const float scale = s2/(1.f+s2) * rsqrtf(s2 + 1e-7f);
  const float vals[4] = {a0*scale, a1*scale, a2*scale, a3*scale};
#pragma unroll
  for (int q=0;q<4;q++){
    const int kcap = q + 8*t3 + 4*hh;
    if (TR) outp[(i*Kk + kcap)*Bb + b2] = vals[q];
    else    outp[((size_t)b2*Ii + i)*Kk + kcap] = vals[q];
  }
}

// ---- agree pass (bf16 W): br_t (+)= o.u_hat; z[j,b] += exp(br_new) -------
template<int ADD>
__global__ __launch_bounds__(256, 2)
void k_ag(const ushort* __restrict__ Wb, const float* __restrict__ xp,
          const float* __restrict__ ot, float* __restrict__ brt,
          float* __restrict__ zp)
{
  const int t  = threadIdx.x;
  const int w  = t >> 6, lane = t & 63;
  const int kk = lane & 31;
  const int h  = lane >> 5;
  const int b  = lane & 31;
  const int i0 = blockIdx.y * 4;
  const int j0 = blockIdx.x * 16 + w * 4;

  bf16x8 Bh[4], Bl[4];
#pragma unroll
  for (int jj=0;jj<4;jj++){
    const int j = j0 + jj;
    float x8[8];
    *(f32x4*)(x8)   = *(const f32x4*)(xp + (b*Jj + j)*16 + h*8);
    *(f32x4*)(x8+4) = *(const f32x4*)(xp + (b*Jj + j)*16 + h*8 + 4);
    split8(x8, Bh[jj], Bl[jj]);
  }

  float ez[4] = {0.f, 0.f, 0.f, 0.f};

#pragma unroll
  for (int ii=0; ii<4; ++ii){
    const int i = i0 + ii;
    float ov[16];
#pragma unroll
    for (int r=0;r<16;r++){
      const int kcap = (r & 3) + 8*(r >> 2) + 4*h;
      ov[r] = ot[(i*Kk + kcap)*Bb + b];
    }
#pragma unroll
    for (int jj=0;jj<4;jj++){
      const size_t eoff = (size_t)(i*Jj + j0+jj)*512 + kk*16 + h*8;
      const bf16x8 Ah = *reinterpret_cast<const bf16x8*>(Wb + eoff);
      f32x16 d = {};
      d = MFMA(Ah, Bh[jj], d);
      d = MFMA(Ah, Bl[jj], d);
      float ap = 0.f;
#pragma unroll
      for (int r=0;r<16;r++) ap += ov[r]*d[r];
      ap += __shfl_xor(ap, 32);
      if (h == 0){
        const int idx = (i*Jj + j0+jj)*32 + b;
        const float prev = ADD ? brt[idx] : 0.f;
        const float bn = prev + ap;
        brt[idx] = bn;
        ez[jj] += __expf(bn);
      }
    }
  }
  if (h == 0){
#pragma unroll
    for (int jj=0;jj<4;jj++)
      atomicAdd(&zp[(j0+jj)*32 + b], ez[jj]);
  }
}

extern "C" void kernel_launch(void* const* d_in, const int* in_sizes, int n_in,
                              void* d_out, int out_size, void* d_ws, size_t ws_size,
                              hipStream_t stream)
{
  const float* x  = (const float*)d_in[0];   // [B,J,M]
  const float* Wp = (const float*)d_in[1];   // [I,J,K,M]
  float* out = (float*)d_out;                // [B,I,K]
  float* ws  = (float*)d_ws;
  ushort* spart = (ushort*)ws;               // 72*64*1024 ushorts (9.4MB)
  float* br    = ws + 2359296;               // 2359296 floats
  float* z     = ws + 4718592;               // 36864 floats
  float* ot    = ws + 4755456;               // 65536 floats
  ushort* Wbf  = (ushort*)(ws + 4820992);    // 37748736 ushorts (75.5MB)

  dim3 gs(NJB2, 16), bs(256);

  // iter 0 (c uniform 1/64); k_s<1> also emits bf16 W
  k_s<1><<<gs, bs, 0, stream>>>(Wp, nullptr, Wbf, x, nullptr, nullptr, spart);
  k_redsq<1><<<dim3(64), bs, 0, stream>>>(spart, ot);
  hipMemsetAsync(z, 0, 36864*sizeof(float), stream);
  k_ag<0><<<gs, bs, 0, stream>>>(Wbf, x, ot, br, z);

  // iter 1
  k_s<0><<<gs, bs, 0, stream>>>(nullptr, Wbf, nullptr, x, br, z, spart);
  k_redsq<1><<<dim3(64), bs, 0, stream>>>(spart, ot);
  hipMemsetAsync(z, 0, 36864*sizeof(float), stream);
  k_ag<1><<<gs, bs, 0, stream>>>(Wbf, x, ot, br, z);

  // iter 2
  k_s<0><<<gs, bs, 0, stream>>>(nullptr, Wbf, nullptr, x, br, z, spart);
  k_redsq<0><<<dim3(64), bs, 0, stream>>>(spart, out);
}